// Round 3
// baseline (1139.824 us; speedup 1.0000x reference)
//
#include <hip/hip_runtime.h>

#define DEV __device__ __forceinline__

typedef __attribute__((ext_vector_type(4))) float f32x4;
typedef __attribute__((ext_vector_type(8))) short short8;
typedef __attribute__((ext_vector_type(4))) unsigned int u32x4;
typedef __attribute__((ext_vector_type(4))) unsigned short us16x4;

#define D_ 768
#define S_ 1024
#define B_ 2
#define H_ 12
#define G_ 4
#define DH_ 64
#define E_ 8
#define F_ 3072
#define NTOK (B_*S_)   // 2048

DEV unsigned short f2bf(float f){
  unsigned int b = __float_as_uint(f);
  b += 0x7FFFu + ((b >> 16) & 1u);
  return (unsigned short)(b >> 16);
}
DEV float bf2f(unsigned short h){ return __uint_as_float(((unsigned int)h) << 16); }
// returns lo<<16 | hi packed; hi = bf16(v), lo = bf16(v - hi)
DEV unsigned int splitbf_pack(float v){
  unsigned short h = f2bf(v);
  unsigned short l = f2bf(v - bf2f(h));
  return (unsigned int)h | ((unsigned int)l << 16);
}

// ---------------- transpose-cast-split: W[K][N] fp32 -> Wh/Wl[N][K] bf16 ----------------
__global__ __launch_bounds__(256) void tcast_kernel(const float* __restrict__ W,
                                                    unsigned short* __restrict__ Wh,
                                                    unsigned short* __restrict__ Wl,
                                                    int K, int N){
  __shared__ float tile[32][33];
  long long zoff = (long long)blockIdx.z * K * N;
  const float* Wz = W + zoff;
  int n0 = blockIdx.x*32, k0 = blockIdx.y*32;
  int tx = threadIdx.x, ty = threadIdx.y;
  #pragma unroll
  for (int i=0;i<4;i++){
    int r = ty + i*8;
    tile[r][tx] = Wz[(long long)(k0+r)*N + n0 + tx];
  }
  __syncthreads();
  #pragma unroll
  for (int i=0;i<4;i++){
    int r = ty + i*8;
    float v = tile[tx][r];
    unsigned int hl = splitbf_pack(v);
    long long o = zoff + (long long)(n0+r)*K + k0 + tx;
    Wh[o] = (unsigned short)(hl & 0xFFFFu);
    if (Wl) Wl[o] = (unsigned short)(hl >> 16);
  }
}

// ---------------- LayerNorm: 1 block per row, D=768; fp32 out + optional bf16 out ----------------
__global__ __launch_bounds__(256) void ln_kernel(const float* __restrict__ x,
                                                 const float* __restrict__ sc,
                                                 const float* __restrict__ bi,
                                                 unsigned short* __restrict__ outb,
                                                 float* __restrict__ outf){
  __shared__ float red[8];
  long long row = blockIdx.x;
  const float* xr = x + row*D_;
  int tid = threadIdx.x;
  float v0 = xr[tid], v1 = xr[tid+256], v2 = xr[tid+512];
  float s = v0+v1+v2;
  float q = v0*v0 + v1*v1 + v2*v2;
  #pragma unroll
  for (int off=32; off; off>>=1){ s += __shfl_xor(s, off); q += __shfl_xor(q, off); }
  int lane = tid & 63, w = tid >> 6;
  if (lane == 0){ red[w] = s; red[4+w] = q; }
  __syncthreads();
  s = red[0]+red[1]+red[2]+red[3];
  q = red[4]+red[5]+red[6]+red[7];
  float mu  = s * (1.0f/D_);
  float var = q * (1.0f/D_) - mu*mu;
  float rstd = rsqrtf(var + 1e-6f);
  #pragma unroll
  for (int i=0;i<3;i++){
    int idx = tid + 256*i;
    float vv = (i==0) ? v0 : (i==1) ? v1 : v2;
    float o = (vv - mu)*rstd*sc[idx] + bi[idx];
    outf[row*D_ + idx] = o;
    if (outb) outb[row*D_ + idx] = f2bf(o);
  }
}

// ---------------- split bf16x3 NT GEMM: C = A(fp32) @ W(fp32 via hi+lo bf16)^T ----------------
// A fp32 [M][lda]; Wh/Wl bf16 [N][K]; out fp32 (+bias, +resid). 64x64 tile, BK=64.
#define LDK 80
__global__ __launch_bounds__(256) void gemm_split(
    const float* __restrict__ A, int lda,
    const unsigned short* __restrict__ Wh,
    const unsigned short* __restrict__ Wl,
    const float* __restrict__ bias,
    const float* __restrict__ resid,
    float* __restrict__ Cf, int ldc,
    int K)
{
  __shared__ __align__(16) unsigned short Ash[64*LDK];
  __shared__ __align__(16) unsigned short Asl[64*LDK];
  __shared__ __align__(16) unsigned short Bsh[64*LDK];
  __shared__ __align__(16) unsigned short Bsl[64*LDK];
  const int r0 = blockIdx.y*64;
  const int n0 = blockIdx.x*64;
  const int tid = threadIdx.x;
  const int lane = tid & 63;
  const int wv = tid >> 6;
  const int wr = (wv>>1)*32, wc = (wv&1)*32;

  f32x4 acc[2][2];
  #pragma unroll
  for (int i=0;i<2;i++)
    #pragma unroll
    for (int j=0;j<2;j++) acc[i][j] = (f32x4){0.f,0.f,0.f,0.f};

  for (int k0 = 0; k0 < K; k0 += 64){
    #pragma unroll
    for (int i=0;i<2;i++){
      int c = tid + i*256;
      int rr = c >> 3;
      int kc = (c & 7) * 8;
      const float* ap = A + (long long)(r0+rr)*lda + k0 + kc;
      f32x4 a0 = *(const f32x4*)(ap);
      f32x4 a1 = *(const f32x4*)(ap + 4);
      unsigned int p0 = splitbf_pack(a0.x), p1 = splitbf_pack(a0.y);
      unsigned int p2 = splitbf_pack(a0.z), p3 = splitbf_pack(a0.w);
      unsigned int p4 = splitbf_pack(a1.x), p5 = splitbf_pack(a1.y);
      unsigned int p6 = splitbf_pack(a1.z), p7 = splitbf_pack(a1.w);
      us16x4 h0, h1, l0, l1;
      h0.x=(unsigned short)p0; l0.x=(unsigned short)(p0>>16);
      h0.y=(unsigned short)p1; l0.y=(unsigned short)(p1>>16);
      h0.z=(unsigned short)p2; l0.z=(unsigned short)(p2>>16);
      h0.w=(unsigned short)p3; l0.w=(unsigned short)(p3>>16);
      h1.x=(unsigned short)p4; l1.x=(unsigned short)(p4>>16);
      h1.y=(unsigned short)p5; l1.y=(unsigned short)(p5>>16);
      h1.z=(unsigned short)p6; l1.z=(unsigned short)(p6>>16);
      h1.w=(unsigned short)p7; l1.w=(unsigned short)(p7>>16);
      *(us16x4*)&Ash[rr*LDK + kc]     = h0;
      *(us16x4*)&Ash[rr*LDK + kc + 4] = h1;
      *(us16x4*)&Asl[rr*LDK + kc]     = l0;
      *(us16x4*)&Asl[rr*LDK + kc + 4] = l1;
      long long bo = (long long)(n0+rr)*K + k0 + kc;
      *(u32x4*)&Bsh[rr*LDK + kc] = *(const u32x4*)(Wh + bo);
      *(u32x4*)&Bsl[rr*LDK + kc] = *(const u32x4*)(Wl + bo);
    }
    __syncthreads();
    #pragma unroll
    for (int ks=0; ks<2; ks++){
      int koff = ks*32 + (lane>>4)*8;
      short8 ah0 = *(const short8*)&Ash[(wr +      (lane&15))*LDK + koff];
      short8 ah1 = *(const short8*)&Ash[(wr + 16 + (lane&15))*LDK + koff];
      short8 al0 = *(const short8*)&Asl[(wr +      (lane&15))*LDK + koff];
      short8 al1 = *(const short8*)&Asl[(wr + 16 + (lane&15))*LDK + koff];
      short8 bh0 = *(const short8*)&Bsh[(wc +      (lane&15))*LDK + koff];
      short8 bh1 = *(const short8*)&Bsh[(wc + 16 + (lane&15))*LDK + koff];
      short8 bl0 = *(const short8*)&Bsl[(wc +      (lane&15))*LDK + koff];
      short8 bl1 = *(const short8*)&Bsl[(wc + 16 + (lane&15))*LDK + koff];
      acc[0][0] = __builtin_amdgcn_mfma_f32_16x16x32_bf16(ah0, bh0, acc[0][0], 0,0,0);
      acc[0][1] = __builtin_amdgcn_mfma_f32_16x16x32_bf16(ah0, bh1, acc[0][1], 0,0,0);
      acc[1][0] = __builtin_amdgcn_mfma_f32_16x16x32_bf16(ah1, bh0, acc[1][0], 0,0,0);
      acc[1][1] = __builtin_amdgcn_mfma_f32_16x16x32_bf16(ah1, bh1, acc[1][1], 0,0,0);
      acc[0][0] = __builtin_amdgcn_mfma_f32_16x16x32_bf16(ah0, bl0, acc[0][0], 0,0,0);
      acc[0][1] = __builtin_amdgcn_mfma_f32_16x16x32_bf16(ah0, bl1, acc[0][1], 0,0,0);
      acc[1][0] = __builtin_amdgcn_mfma_f32_16x16x32_bf16(ah1, bl0, acc[1][0], 0,0,0);
      acc[1][1] = __builtin_amdgcn_mfma_f32_16x16x32_bf16(ah1, bl1, acc[1][1], 0,0,0);
      acc[0][0] = __builtin_amdgcn_mfma_f32_16x16x32_bf16(al0, bh0, acc[0][0], 0,0,0);
      acc[0][1] = __builtin_amdgcn_mfma_f32_16x16x32_bf16(al0, bh1, acc[0][1], 0,0,0);
      acc[1][0] = __builtin_amdgcn_mfma_f32_16x16x32_bf16(al1, bh0, acc[1][0], 0,0,0);
      acc[1][1] = __builtin_amdgcn_mfma_f32_16x16x32_bf16(al1, bh1, acc[1][1], 0,0,0);
    }
    __syncthreads();
  }

  // epilogue: col = lane&15, row = (lane>>4)*4 + reg
  #pragma unroll
  for (int fi=0; fi<2; fi++)
  #pragma unroll
  for (int fj=0; fj<2; fj++)
  #pragma unroll
  for (int reg=0; reg<4; reg++){
    int r = r0 + wr + fi*16 + (lane>>4)*4 + reg;
    int col = n0 + wc + fj*16 + (lane&15);
    float val = acc[fi][fj][reg] + bias[col];
    if (resid) val += resid[(long long)r*ldc + col];
    Cf[(long long)r*ldc + col] = val;
  }
}

// ---------------- plain bf16 NT GEMM for MoE experts (gather, gelu, bf16/f32 out) ----------------
__global__ __launch_bounds__(256) void gemm_nt(
    const unsigned short* __restrict__ A, int lda,
    const unsigned short* __restrict__ Wt, long long wstride,
    const float* __restrict__ bias, int bias_stride,
    const int* __restrict__ counts,
    const int* __restrict__ a_idx, int a_idx_stride,
    const int* __restrict__ row_base,
    float* __restrict__ Cf, unsigned short* __restrict__ Cb, int ldc,
    int M, int K, int do_gelu)
{
  __shared__ __align__(16) unsigned short As[64*LDK];
  __shared__ __align__(16) unsigned short Bs[64*LDK];
  const int z = blockIdx.z;
  const int Mz = counts ? counts[z] : M;
  const int r0 = blockIdx.y*64;
  if (r0 >= Mz) return;
  const int n0 = blockIdx.x*64;
  const int obase = row_base ? row_base[z] : 0;
  const unsigned short* Wz = Wt + (long long)z*wstride;
  const float* bz = bias + (long long)z*bias_stride;
  const int tid = threadIdx.x;
  const int lane = tid & 63;
  const int wv = tid >> 6;
  const int wr = (wv>>1)*32, wc = (wv&1)*32;

  long long arow[2];
  #pragma unroll
  for (int i=0;i<2;i++){
    int c = tid + i*256;
    int rr = c >> 3;
    int r = r0 + rr;
    int rcl = (r < Mz) ? r : (Mz-1);
    arow[i] = a_idx ? (long long)a_idx[(long long)z*a_idx_stride + rcl]
                    : (long long)(obase + rcl);
  }

  f32x4 acc[2][2];
  #pragma unroll
  for (int i=0;i<2;i++)
    #pragma unroll
    for (int j=0;j<2;j++) acc[i][j] = (f32x4){0.f,0.f,0.f,0.f};

  for (int k0 = 0; k0 < K; k0 += 64){
    #pragma unroll
    for (int i=0;i<2;i++){
      int c = tid + i*256;
      int rr = c >> 3;
      int kc = (c & 7) * 8;
      *(u32x4*)&As[rr*LDK + kc] = *(const u32x4*)(A + arow[i]*lda + k0 + kc);
      *(u32x4*)&Bs[rr*LDK + kc] = *(const u32x4*)(Wz + (long long)(n0+rr)*K + k0 + kc);
    }
    __syncthreads();
    #pragma unroll
    for (int ks=0; ks<2; ks++){
      int koff = ks*32 + (lane>>4)*8;
      short8 a0 = *(const short8*)&As[(wr +      (lane&15))*LDK + koff];
      short8 a1 = *(const short8*)&As[(wr + 16 + (lane&15))*LDK + koff];
      short8 b0 = *(const short8*)&Bs[(wc +      (lane&15))*LDK + koff];
      short8 b1 = *(const short8*)&Bs[(wc + 16 + (lane&15))*LDK + koff];
      acc[0][0] = __builtin_amdgcn_mfma_f32_16x16x32_bf16(a0, b0, acc[0][0], 0,0,0);
      acc[0][1] = __builtin_amdgcn_mfma_f32_16x16x32_bf16(a0, b1, acc[0][1], 0,0,0);
      acc[1][0] = __builtin_amdgcn_mfma_f32_16x16x32_bf16(a1, b0, acc[1][0], 0,0,0);
      acc[1][1] = __builtin_amdgcn_mfma_f32_16x16x32_bf16(a1, b1, acc[1][1], 0,0,0);
    }
    __syncthreads();
  }

  #pragma unroll
  for (int fi=0; fi<2; fi++)
  #pragma unroll
  for (int fj=0; fj<2; fj++)
  #pragma unroll
  for (int reg=0; reg<4; reg++){
    int ml = wr + fi*16 + (lane>>4)*4 + reg;
    int r = r0 + ml;
    if (r >= Mz) continue;
    int col = n0 + wc + fj*16 + (lane&15);
    float val = acc[fi][fj][reg] + bz[col];
    if (do_gelu){
      float xx = val;
      float t = tanhf(0.7978845608028654f*(xx + 0.044715f*xx*xx*xx));
      val = 0.5f*xx*(1.0f + t);
    }
    long long orow = (long long)obase + r;
    if (Cf) Cf[orow*ldc + col] = val;
    if (Cb) Cb[orow*ldc + col] = f2bf(val);
  }
}

// ---------------- attention: fp32, scores in LDS, fp32 ctx out ----------------
__global__ __launch_bounds__(256) void attn_kernel(const float* __restrict__ q,
                                                   const float* __restrict__ k,
                                                   const float* __restrict__ v,
                                                   float* __restrict__ ctx,
                                                   int causal){
  __shared__ float sS[32][1024];   // 128 KB
  __shared__ float qs[32][64];     // 8 KB
  __shared__ float inv_s[32];
  const int qs0 = blockIdx.x*32;
  const int h = blockIdx.y;
  const int b = blockIdx.z;
  const int g = h / (H_/G_);

  for (int i = threadIdx.x; i < 32*64; i += 256){
    int r = i >> 6, d = i & 63;
    qs[r][d] = q[((long long)(b*S_ + qs0 + r))*D_ + h*DH_ + d];
  }
  __syncthreads();

  for (int idx = threadIdx.x; idx < 8*1024; idx += 256){
    int kj = idx & 1023;
    int qg = idx >> 10;
    const float* kr = k + ((long long)(b*S_ + kj))*(G_*DH_) + g*DH_;
    float a0=0.f, a1=0.f, a2=0.f, a3=0.f;
    #pragma unroll
    for (int d4=0; d4<16; d4++){
      f32x4 kv = *(const f32x4*)(kr + d4*4);
      f32x4 q0v = *(const f32x4*)&qs[qg*4+0][d4*4];
      f32x4 q1v = *(const f32x4*)&qs[qg*4+1][d4*4];
      f32x4 q2v = *(const f32x4*)&qs[qg*4+2][d4*4];
      f32x4 q3v = *(const f32x4*)&qs[qg*4+3][d4*4];
      a0 += q0v.x*kv.x + q0v.y*kv.y + q0v.z*kv.z + q0v.w*kv.w;
      a1 += q1v.x*kv.x + q1v.y*kv.y + q1v.z*kv.z + q1v.w*kv.w;
      a2 += q2v.x*kv.x + q2v.y*kv.y + q2v.z*kv.z + q2v.w*kv.w;
      a3 += q3v.x*kv.x + q3v.y*kv.y + q3v.z*kv.z + q3v.w*kv.w;
    }
    int qb = qs0 + qg*4;
    sS[qg*4+0][kj] = (causal && kj > qb+0) ? -3.0e38f : a0*0.125f;
    sS[qg*4+1][kj] = (causal && kj > qb+1) ? -3.0e38f : a1*0.125f;
    sS[qg*4+2][kj] = (causal && kj > qb+2) ? -3.0e38f : a2*0.125f;
    sS[qg*4+3][kj] = (causal && kj > qb+3) ? -3.0e38f : a3*0.125f;
  }
  __syncthreads();

  {
    int row = threadIdx.x >> 3;
    int j = threadIdx.x & 7;
    float m = -3.0e38f;
    for (int kk=j; kk<1024; kk+=8) m = fmaxf(m, sS[row][kk]);
    #pragma unroll
    for (int off=1; off<8; off<<=1) m = fmaxf(m, __shfl_xor(m, off));
    float sum = 0.f;
    for (int kk=j; kk<1024; kk+=8){
      float pv = __expf(sS[row][kk] - m);
      sS[row][kk] = pv;
      sum += pv;
    }
    #pragma unroll
    for (int off=1; off<8; off<<=1) sum += __shfl_xor(sum, off);
    if (j == 0) inv_s[row] = 1.0f/sum;
  }
  __syncthreads();

  {
    int d = threadIdx.x & 63;
    int wvi = threadIdx.x >> 6;
    float acc[8];
    #pragma unroll
    for (int r=0;r<8;r++) acc[r] = 0.f;
    const float* vb = v + ((long long)(b*S_))*(G_*DH_) + g*DH_ + d;
    for (int kj=0; kj<1024; kj+=4){
      float v0 = vb[(long long)(kj+0)*(G_*DH_)];
      float v1 = vb[(long long)(kj+1)*(G_*DH_)];
      float v2 = vb[(long long)(kj+2)*(G_*DH_)];
      float v3 = vb[(long long)(kj+3)*(G_*DH_)];
      #pragma unroll
      for (int r=0;r<8;r++){
        f32x4 p4 = *(const f32x4*)&sS[wvi*8+r][kj];
        acc[r] += p4.x*v0 + p4.y*v1 + p4.z*v2 + p4.w*v3;
      }
    }
    #pragma unroll
    for (int r=0;r<8;r++){
      int qi = wvi*8 + r;
      ctx[((long long)(b*S_ + qs0 + qi))*D_ + h*DH_ + d] = acc[r]*inv_s[qi];
    }
  }
}

// ---------------- MoE gate: fp32 logits, top-2, routing ----------------
__global__ __launch_bounds__(256) void gate_kernel(const float* __restrict__ xnf,
                                                   const float* __restrict__ gw,
                                                   const float* __restrict__ gb,
                                                   int* __restrict__ counts,
                                                   int* __restrict__ toklist,
                                                   int* __restrict__ route_e,
                                                   int* __restrict__ route_pos,
                                                   float* __restrict__ route_w){
  int t = blockIdx.x*4 + (threadIdx.x >> 6);
  int lane = threadIdx.x & 63;
  float acc[E_];
  #pragma unroll
  for (int e=0;e<E_;e++) acc[e] = 0.f;
  #pragma unroll
  for (int i=0;i<12;i++){
    int d = lane + 64*i;
    float xv = xnf[(long long)t*D_ + d];
    const float* w = gw + (long long)d*E_;
    #pragma unroll
    for (int e=0;e<E_;e++) acc[e] += xv*w[e];
  }
  #pragma unroll
  for (int off=32; off; off>>=1)
    #pragma unroll
    for (int e=0;e<E_;e++) acc[e] += __shfl_xor(acc[e], off);
  if (lane == 0){
    #pragma unroll
    for (int e=0;e<E_;e++) acc[e] += gb[e];
    int e0 = 0;
    #pragma unroll
    for (int e=1;e<E_;e++) if (acc[e] > acc[e0]) e0 = e;
    int e1 = -1;
    #pragma unroll
    for (int e=0;e<E_;e++) if (e != e0 && (e1 < 0 || acc[e] > acc[e1])) e1 = e;
    float w0 = 1.0f/(1.0f + __expf(acc[e1] - acc[e0]));
    float w1 = 1.0f - w0;
    int p0 = atomicAdd(&counts[e0], 1);
    int p1 = atomicAdd(&counts[e1], 1);
    toklist[e0*NTOK + p0] = t;
    toklist[e1*NTOK + p1] = t;
    route_e[2*t]   = e0; route_e[2*t+1]   = e1;
    route_pos[2*t] = p0; route_pos[2*t+1] = p1;
    route_w[2*t]   = w0; route_w[2*t+1]   = w1;
  }
}

__global__ void offsets_kernel(const int* __restrict__ counts, int* __restrict__ offs){
  if (threadIdx.x == 0){
    int s = 0;
    for (int e=0;e<E_;e++){ offs[e] = s; s += counts[e]; }
  }
}

__global__ __launch_bounds__(192) void combine_kernel(const float* __restrict__ xb,
                                                      const float* __restrict__ y,
                                                      const int* __restrict__ route_e,
                                                      const int* __restrict__ route_pos,
                                                      const float* __restrict__ route_w,
                                                      const int* __restrict__ offs,
                                                      float* __restrict__ out){
  int t = blockIdx.x;
  int i = threadIdx.x;
  int e0 = route_e[2*t], e1 = route_e[2*t+1];
  long long s0 = offs[e0] + route_pos[2*t];
  long long s1 = offs[e1] + route_pos[2*t+1];
  float w0 = route_w[2*t], w1 = route_w[2*t+1];
  f32x4 xv = *(const f32x4*)(xb + (long long)t*D_ + i*4);
  f32x4 y0 = *(const f32x4*)(y + s0*D_ + i*4);
  f32x4 y1 = *(const f32x4*)(y + s1*D_ + i*4);
  f32x4 o = xv + w0*y0 + w1*y1;
  *(f32x4*)(out + (long long)t*D_ + i*4) = o;
}

// ---------------- host orchestration ----------------
extern "C" void kernel_launch(void* const* d_in, const int* in_sizes, int n_in,
                              void* d_out, int out_size, void* d_ws, size_t ws_size,
                              hipStream_t stream) {
  (void)in_sizes; (void)n_in; (void)out_size; (void)ws_size;
  const float* x     = (const float*)d_in[0];
  const float* enc   = (const float*)d_in[1];
  const float* ln1s  = (const float*)d_in[2];
  const float* ln1b  = (const float*)d_in[3];
  const float* ln2s  = (const float*)d_in[4];
  const float* ln2b  = (const float*)d_in[5];
  const float* ln3s  = (const float*)d_in[6];
  const float* ln3b  = (const float*)d_in[7];
  const float* sa_wq = (const float*)d_in[8];
  const float* sa_bq = (const float*)d_in[9];
  const float* sa_wk = (const float*)d_in[10];
  const float* sa_bk = (const float*)d_in[11];
  const float* sa_wv = (const float*)d_in[12];
  const float* sa_bv = (const float*)d_in[13];
  const float* sa_wo = (const float*)d_in[14];
  const float* sa_bo = (const float*)d_in[15];
  const float* ca_wq = (const float*)d_in[16];
  const float* ca_bq = (const float*)d_in[17];
  const float* ca_wk = (const float*)d_in[18];
  const float* ca_bk = (const float*)d_in[19];
  const float* ca_wv = (const float*)d_in[20];
  const float* ca_bv = (const float*)d_in[21];
  const float* ca_wo = (const float*)d_in[22];
  const float* ca_bo = (const float*)d_in[23];
  const float* gate_w= (const float*)d_in[24];
  const float* gate_b= (const float*)d_in[25];
  const float* w1    = (const float*)d_in[26];
  const float* b1    = (const float*)d_in[27];
  const float* w2    = (const float*)d_in[28];
  const float* b2    = (const float*)d_in[29];
  float* out = (float*)d_out;

  char* p = (char*)d_ws;
  auto alloc = [&](size_t bytes)->void*{
    void* r = (void*)p;
    p += (bytes + 255) & ~(size_t)255;
    return r;
  };
  unsigned short* wqh_sa = (unsigned short*)alloc((size_t)D_*D_*2);
  unsigned short* wql_sa = (unsigned short*)alloc((size_t)D_*D_*2);
  unsigned short* wkh_sa = (unsigned short*)alloc((size_t)D_*G_*DH_*2);
  unsigned short* wkl_sa = (unsigned short*)alloc((size_t)D_*G_*DH_*2);
  unsigned short* wvh_sa = (unsigned short*)alloc((size_t)D_*G_*DH_*2);
  unsigned short* wvl_sa = (unsigned short*)alloc((size_t)D_*G_*DH_*2);
  unsigned short* woh_sa = (unsigned short*)alloc((size_t)D_*D_*2);
  unsigned short* wol_sa = (unsigned short*)alloc((size_t)D_*D_*2);
  unsigned short* wqh_ca = (unsigned short*)alloc((size_t)D_*D_*2);
  unsigned short* wql_ca = (unsigned short*)alloc((size_t)D_*D_*2);
  unsigned short* wkh_ca = (unsigned short*)alloc((size_t)D_*G_*DH_*2);
  unsigned short* wkl_ca = (unsigned short*)alloc((size_t)D_*G_*DH_*2);
  unsigned short* wvh_ca = (unsigned short*)alloc((size_t)D_*G_*DH_*2);
  unsigned short* wvl_ca = (unsigned short*)alloc((size_t)D_*G_*DH_*2);
  unsigned short* woh_ca = (unsigned short*)alloc((size_t)D_*D_*2);
  unsigned short* wol_ca = (unsigned short*)alloc((size_t)D_*D_*2);
  unsigned short* w1T = (unsigned short*)alloc((size_t)E_*D_*F_*2);
  unsigned short* w2T = (unsigned short*)alloc((size_t)E_*D_*F_*2);
  unsigned short* xn_b = (unsigned short*)alloc((size_t)NTOK*D_*2);
  unsigned short* hbuf = (unsigned short*)alloc((size_t)2*NTOK*F_*2);
  float* xnf  = (float*)alloc((size_t)NTOK*D_*4);
  float* qbuf = (float*)alloc((size_t)NTOK*D_*4);
  float* kbuf = (float*)alloc((size_t)NTOK*G_*DH_*4);
  float* vbuf = (float*)alloc((size_t)NTOK*G_*DH_*4);
  float* ctx  = (float*)alloc((size_t)NTOK*D_*4);
  float* xbuf = (float*)alloc((size_t)NTOK*D_*4);
  float* ybuf = (float*)alloc((size_t)2*NTOK*D_*4);
  int* counts    = (int*)alloc(E_*4);
  int* offs      = (int*)alloc(E_*4);
  int* toklist   = (int*)alloc((size_t)E_*NTOK*4);
  int* route_e   = (int*)alloc((size_t)2*NTOK*4);
  int* route_pos = (int*)alloc((size_t)2*NTOK*4);
  float* route_w = (float*)alloc((size_t)2*NTOK*4);

  (void)hipMemsetAsync(counts, 0, E_*sizeof(int), stream);

  dim3 tb(32,8);
  tcast_kernel<<<dim3(24,24,1), tb, 0, stream>>>(sa_wq, wqh_sa, wql_sa, 768, 768);
  tcast_kernel<<<dim3( 8,24,1), tb, 0, stream>>>(sa_wk, wkh_sa, wkl_sa, 768, 256);
  tcast_kernel<<<dim3( 8,24,1), tb, 0, stream>>>(sa_wv, wvh_sa, wvl_sa, 768, 256);
  tcast_kernel<<<dim3(24,24,1), tb, 0, stream>>>(sa_wo, woh_sa, wol_sa, 768, 768);
  tcast_kernel<<<dim3(24,24,1), tb, 0, stream>>>(ca_wq, wqh_ca, wql_ca, 768, 768);
  tcast_kernel<<<dim3( 8,24,1), tb, 0, stream>>>(ca_wk, wkh_ca, wkl_ca, 768, 256);
  tcast_kernel<<<dim3( 8,24,1), tb, 0, stream>>>(ca_wv, wvh_ca, wvl_ca, 768, 256);
  tcast_kernel<<<dim3(24,24,1), tb, 0, stream>>>(ca_wo, woh_ca, wol_ca, 768, 768);
  tcast_kernel<<<dim3(96,24,E_), tb, 0, stream>>>(w1, w1T, nullptr, 768, 3072);
  tcast_kernel<<<dim3(24,96,E_), tb, 0, stream>>>(w2, w2T, nullptr, 3072, 768);

  // ---- self-attention (split-precision path) ----
  ln_kernel<<<NTOK, 256, 0, stream>>>(x, ln1s, ln1b, nullptr, xnf);
  gemm_split<<<dim3(12,32), 256, 0, stream>>>(xnf, 768, wqh_sa, wql_sa, sa_bq, nullptr, qbuf, 768, 768);
  gemm_split<<<dim3( 4,32), 256, 0, stream>>>(xnf, 768, wkh_sa, wkl_sa, sa_bk, nullptr, kbuf, 256, 768);
  gemm_split<<<dim3( 4,32), 256, 0, stream>>>(xnf, 768, wvh_sa, wvl_sa, sa_bv, nullptr, vbuf, 256, 768);
  attn_kernel<<<dim3(32,12,2), 256, 0, stream>>>(qbuf, kbuf, vbuf, ctx, 1);
  gemm_split<<<dim3(12,32), 256, 0, stream>>>(ctx, 768, woh_sa, wol_sa, sa_bo, x, xbuf, 768, 768);

  // ---- cross-attention ----
  ln_kernel<<<NTOK, 256, 0, stream>>>(xbuf, ln2s, ln2b, nullptr, xnf);
  gemm_split<<<dim3(12,32), 256, 0, stream>>>(xnf, 768, wqh_ca, wql_ca, ca_bq, nullptr, qbuf, 768, 768);
  gemm_split<<<dim3( 4,32), 256, 0, stream>>>(enc, 768, wkh_ca, wkl_ca, ca_bk, nullptr, kbuf, 256, 768);
  gemm_split<<<dim3( 4,32), 256, 0, stream>>>(enc, 768, wvh_ca, wvl_ca, ca_bv, nullptr, vbuf, 256, 768);
  attn_kernel<<<dim3(32,12,2), 256, 0, stream>>>(qbuf, kbuf, vbuf, ctx, 0);
  gemm_split<<<dim3(12,32), 256, 0, stream>>>(ctx, 768, woh_ca, wol_ca, ca_bo, xbuf, xbuf, 768, 768);

  // ---- MoE ----
  ln_kernel<<<NTOK, 256, 0, stream>>>(xbuf, ln3s, ln3b, xn_b, xnf);
  gate_kernel<<<NTOK/4, 256, 0, stream>>>(xnf, gate_w, gate_b,
      counts, toklist, route_e, route_pos, route_w);
  offsets_kernel<<<1, 64, 0, stream>>>(counts, offs);
  gemm_nt<<<dim3(48,32,E_), 256, 0, stream>>>(xn_b, 768, w1T, (long long)F_*D_, b1, F_,
      counts, toklist, NTOK, offs, nullptr, hbuf, F_, NTOK, 768, 1);
  gemm_nt<<<dim3(12,32,E_), 256, 0, stream>>>(hbuf, F_, w2T, (long long)F_*D_, b2, D_,
      counts, nullptr, 0, offs, ybuf, nullptr, 768, NTOK, F_, 0);
  combine_kernel<<<NTOK, 192, 0, stream>>>(xbuf, ybuf, route_e, route_pos, route_w, offs, out);
}

// Round 4
// 537.337 us; speedup vs baseline: 2.1212x; 2.1212x over previous
//
#include <hip/hip_runtime.h>

#define DEV __device__ __forceinline__

typedef __attribute__((ext_vector_type(4))) float f32x4;
typedef __attribute__((ext_vector_type(8))) short short8;
typedef __attribute__((ext_vector_type(4))) unsigned int u32x4;
typedef __attribute__((ext_vector_type(4))) unsigned short us16x4;

#define D_ 768
#define S_ 1024
#define B_ 2
#define H_ 12
#define G_ 4
#define DH_ 64
#define E_ 8
#define F_ 3072
#define NTOK (B_*S_)   // 2048

DEV unsigned short f2bf(float f){
  unsigned int b = __float_as_uint(f);
  b += 0x7FFFu + ((b >> 16) & 1u);
  return (unsigned short)(b >> 16);
}
DEV float bf2f(unsigned short h){ return __uint_as_float(((unsigned int)h) << 16); }
// returns lo<<16 | hi packed; hi = bf16(v), lo = bf16(v - hi)
DEV unsigned int splitbf_pack(float v){
  unsigned short h = f2bf(v);
  unsigned short l = f2bf(v - bf2f(h));
  return (unsigned int)h | ((unsigned int)l << 16);
}

// ---------------- transpose-cast-split: W[K][N] fp32 -> Wh/Wl[N][K] bf16 ----------------
__global__ __launch_bounds__(256) void tcast_kernel(const float* __restrict__ W,
                                                    unsigned short* __restrict__ Wh,
                                                    unsigned short* __restrict__ Wl,
                                                    int K, int N){
  __shared__ float tile[32][33];
  long long zoff = (long long)blockIdx.z * K * N;
  const float* Wz = W + zoff;
  int n0 = blockIdx.x*32, k0 = blockIdx.y*32;
  int tx = threadIdx.x, ty = threadIdx.y;
  #pragma unroll
  for (int i=0;i<4;i++){
    int r = ty + i*8;
    tile[r][tx] = Wz[(long long)(k0+r)*N + n0 + tx];
  }
  __syncthreads();
  #pragma unroll
  for (int i=0;i<4;i++){
    int r = ty + i*8;
    float v = tile[tx][r];
    unsigned int hl = splitbf_pack(v);
    long long o = zoff + (long long)(n0+r)*K + k0 + tx;
    Wh[o] = (unsigned short)(hl & 0xFFFFu);
    if (Wl) Wl[o] = (unsigned short)(hl >> 16);
  }
}

// ---------------- LayerNorm ----------------
__global__ __launch_bounds__(256) void ln_kernel(const float* __restrict__ x,
                                                 const float* __restrict__ sc,
                                                 const float* __restrict__ bi,
                                                 unsigned short* __restrict__ outb,
                                                 float* __restrict__ outf){
  __shared__ float red[8];
  long long row = blockIdx.x;
  const float* xr = x + row*D_;
  int tid = threadIdx.x;
  float v0 = xr[tid], v1 = xr[tid+256], v2 = xr[tid+512];
  float s = v0+v1+v2;
  float q = v0*v0 + v1*v1 + v2*v2;
  #pragma unroll
  for (int off=32; off; off>>=1){ s += __shfl_xor(s, off); q += __shfl_xor(q, off); }
  int lane = tid & 63, w = tid >> 6;
  if (lane == 0){ red[w] = s; red[4+w] = q; }
  __syncthreads();
  s = red[0]+red[1]+red[2]+red[3];
  q = red[4]+red[5]+red[6]+red[7];
  float mu  = s * (1.0f/D_);
  float var = q * (1.0f/D_) - mu*mu;
  float rstd = rsqrtf(var + 1e-6f);
  #pragma unroll
  for (int i=0;i<3;i++){
    int idx = tid + 256*i;
    float vv = (i==0) ? v0 : (i==1) ? v1 : v2;
    float o = (vv - mu)*rstd*sc[idx] + bi[idx];
    outf[row*D_ + idx] = o;
    if (outb) outb[row*D_ + idx] = f2bf(o);
  }
}

// ---------------- split bf16x3 NT GEMM ----------------
#define LDK 80
__global__ __launch_bounds__(256) void gemm_split(
    const float* __restrict__ A, int lda,
    const unsigned short* __restrict__ Wh,
    const unsigned short* __restrict__ Wl,
    const float* __restrict__ bias,
    const float* __restrict__ resid,
    float* __restrict__ Cf, int ldc,
    int K)
{
  __shared__ __align__(16) unsigned short Ash[64*LDK];
  __shared__ __align__(16) unsigned short Asl[64*LDK];
  __shared__ __align__(16) unsigned short Bsh[64*LDK];
  __shared__ __align__(16) unsigned short Bsl[64*LDK];
  const int r0 = blockIdx.y*64;
  const int n0 = blockIdx.x*64;
  const int tid = threadIdx.x;
  const int lane = tid & 63;
  const int wv = tid >> 6;
  const int wr = (wv>>1)*32, wc = (wv&1)*32;

  f32x4 acc[2][2];
  #pragma unroll
  for (int i=0;i<2;i++)
    #pragma unroll
    for (int j=0;j<2;j++) acc[i][j] = (f32x4){0.f,0.f,0.f,0.f};

  for (int k0 = 0; k0 < K; k0 += 64){
    #pragma unroll
    for (int i=0;i<2;i++){
      int c = tid + i*256;
      int rr = c >> 3;
      int kc = (c & 7) * 8;
      const float* ap = A + (long long)(r0+rr)*lda + k0 + kc;
      f32x4 a0 = *(const f32x4*)(ap);
      f32x4 a1 = *(const f32x4*)(ap + 4);
      unsigned int p0 = splitbf_pack(a0.x), p1 = splitbf_pack(a0.y);
      unsigned int p2 = splitbf_pack(a0.z), p3 = splitbf_pack(a0.w);
      unsigned int p4 = splitbf_pack(a1.x), p5 = splitbf_pack(a1.y);
      unsigned int p6 = splitbf_pack(a1.z), p7 = splitbf_pack(a1.w);
      us16x4 h0, h1, l0, l1;
      h0.x=(unsigned short)p0; l0.x=(unsigned short)(p0>>16);
      h0.y=(unsigned short)p1; l0.y=(unsigned short)(p1>>16);
      h0.z=(unsigned short)p2; l0.z=(unsigned short)(p2>>16);
      h0.w=(unsigned short)p3; l0.w=(unsigned short)(p3>>16);
      h1.x=(unsigned short)p4; l1.x=(unsigned short)(p4>>16);
      h1.y=(unsigned short)p5; l1.y=(unsigned short)(p5>>16);
      h1.z=(unsigned short)p6; l1.z=(unsigned short)(p6>>16);
      h1.w=(unsigned short)p7; l1.w=(unsigned short)(p7>>16);
      *(us16x4*)&Ash[rr*LDK + kc]     = h0;
      *(us16x4*)&Ash[rr*LDK + kc + 4] = h1;
      *(us16x4*)&Asl[rr*LDK + kc]     = l0;
      *(us16x4*)&Asl[rr*LDK + kc + 4] = l1;
      long long bo = (long long)(n0+rr)*K + k0 + kc;
      *(u32x4*)&Bsh[rr*LDK + kc] = *(const u32x4*)(Wh + bo);
      *(u32x4*)&Bsl[rr*LDK + kc] = *(const u32x4*)(Wl + bo);
    }
    __syncthreads();
    #pragma unroll
    for (int ks=0; ks<2; ks++){
      int koff = ks*32 + (lane>>4)*8;
      short8 ah0 = *(const short8*)&Ash[(wr +      (lane&15))*LDK + koff];
      short8 ah1 = *(const short8*)&Ash[(wr + 16 + (lane&15))*LDK + koff];
      short8 al0 = *(const short8*)&Asl[(wr +      (lane&15))*LDK + koff];
      short8 al1 = *(const short8*)&Asl[(wr + 16 + (lane&15))*LDK + koff];
      short8 bh0 = *(const short8*)&Bsh[(wc +      (lane&15))*LDK + koff];
      short8 bh1 = *(const short8*)&Bsh[(wc + 16 + (lane&15))*LDK + koff];
      short8 bl0 = *(const short8*)&Bsl[(wc +      (lane&15))*LDK + koff];
      short8 bl1 = *(const short8*)&Bsl[(wc + 16 + (lane&15))*LDK + koff];
      acc[0][0] = __builtin_amdgcn_mfma_f32_16x16x32_bf16(ah0, bh0, acc[0][0], 0,0,0);
      acc[0][1] = __builtin_amdgcn_mfma_f32_16x16x32_bf16(ah0, bh1, acc[0][1], 0,0,0);
      acc[1][0] = __builtin_amdgcn_mfma_f32_16x16x32_bf16(ah1, bh0, acc[1][0], 0,0,0);
      acc[1][1] = __builtin_amdgcn_mfma_f32_16x16x32_bf16(ah1, bh1, acc[1][1], 0,0,0);
      acc[0][0] = __builtin_amdgcn_mfma_f32_16x16x32_bf16(ah0, bl0, acc[0][0], 0,0,0);
      acc[0][1] = __builtin_amdgcn_mfma_f32_16x16x32_bf16(ah0, bl1, acc[0][1], 0,0,0);
      acc[1][0] = __builtin_amdgcn_mfma_f32_16x16x32_bf16(ah1, bl0, acc[1][0], 0,0,0);
      acc[1][1] = __builtin_amdgcn_mfma_f32_16x16x32_bf16(ah1, bl1, acc[1][1], 0,0,0);
      acc[0][0] = __builtin_amdgcn_mfma_f32_16x16x32_bf16(al0, bh0, acc[0][0], 0,0,0);
      acc[0][1] = __builtin_amdgcn_mfma_f32_16x16x32_bf16(al0, bh1, acc[0][1], 0,0,0);
      acc[1][0] = __builtin_amdgcn_mfma_f32_16x16x32_bf16(al1, bh0, acc[1][0], 0,0,0);
      acc[1][1] = __builtin_amdgcn_mfma_f32_16x16x32_bf16(al1, bh1, acc[1][1], 0,0,0);
    }
    __syncthreads();
  }

  #pragma unroll
  for (int fi=0; fi<2; fi++)
  #pragma unroll
  for (int fj=0; fj<2; fj++)
  #pragma unroll
  for (int reg=0; reg<4; reg++){
    int r = r0 + wr + fi*16 + (lane>>4)*4 + reg;
    int col = n0 + wc + fj*16 + (lane&15);
    float val = acc[fi][fj][reg] + bias[col];
    if (resid) val += resid[(long long)r*ldc + col];
    Cf[(long long)r*ldc + col] = val;
  }
}

// ---------------- plain bf16 NT GEMM for MoE experts ----------------
__global__ __launch_bounds__(256) void gemm_nt(
    const unsigned short* __restrict__ A, int lda,
    const unsigned short* __restrict__ Wt, long long wstride,
    const float* __restrict__ bias, int bias_stride,
    const int* __restrict__ counts,
    const int* __restrict__ a_idx, int a_idx_stride,
    const int* __restrict__ row_base,
    float* __restrict__ Cf, unsigned short* __restrict__ Cb, int ldc,
    int M, int K, int do_gelu)
{
  __shared__ __align__(16) unsigned short As[64*LDK];
  __shared__ __align__(16) unsigned short Bs[64*LDK];
  const int z = blockIdx.z;
  const int Mz = counts ? counts[z] : M;
  const int r0 = blockIdx.y*64;
  if (r0 >= Mz) return;
  const int n0 = blockIdx.x*64;
  const int obase = row_base ? row_base[z] : 0;
  const unsigned short* Wz = Wt + (long long)z*wstride;
  const float* bz = bias + (long long)z*bias_stride;
  const int tid = threadIdx.x;
  const int lane = tid & 63;
  const int wv = tid >> 6;
  const int wr = (wv>>1)*32, wc = (wv&1)*32;

  long long arow[2];
  #pragma unroll
  for (int i=0;i<2;i++){
    int c = tid + i*256;
    int rr = c >> 3;
    int r = r0 + rr;
    int rcl = (r < Mz) ? r : (Mz-1);
    arow[i] = a_idx ? (long long)a_idx[(long long)z*a_idx_stride + rcl]
                    : (long long)(obase + rcl);
  }

  f32x4 acc[2][2];
  #pragma unroll
  for (int i=0;i<2;i++)
    #pragma unroll
    for (int j=0;j<2;j++) acc[i][j] = (f32x4){0.f,0.f,0.f,0.f};

  for (int k0 = 0; k0 < K; k0 += 64){
    #pragma unroll
    for (int i=0;i<2;i++){
      int c = tid + i*256;
      int rr = c >> 3;
      int kc = (c & 7) * 8;
      *(u32x4*)&As[rr*LDK + kc] = *(const u32x4*)(A + arow[i]*lda + k0 + kc);
      *(u32x4*)&Bs[rr*LDK + kc] = *(const u32x4*)(Wz + (long long)(n0+rr)*K + k0 + kc);
    }
    __syncthreads();
    #pragma unroll
    for (int ks=0; ks<2; ks++){
      int koff = ks*32 + (lane>>4)*8;
      short8 a0 = *(const short8*)&As[(wr +      (lane&15))*LDK + koff];
      short8 a1 = *(const short8*)&As[(wr + 16 + (lane&15))*LDK + koff];
      short8 b0 = *(const short8*)&Bs[(wc +      (lane&15))*LDK + koff];
      short8 b1 = *(const short8*)&Bs[(wc + 16 + (lane&15))*LDK + koff];
      acc[0][0] = __builtin_amdgcn_mfma_f32_16x16x32_bf16(a0, b0, acc[0][0], 0,0,0);
      acc[0][1] = __builtin_amdgcn_mfma_f32_16x16x32_bf16(a0, b1, acc[0][1], 0,0,0);
      acc[1][0] = __builtin_amdgcn_mfma_f32_16x16x32_bf16(a1, b0, acc[1][0], 0,0,0);
      acc[1][1] = __builtin_amdgcn_mfma_f32_16x16x32_bf16(a1, b1, acc[1][1], 0,0,0);
    }
    __syncthreads();
  }

  #pragma unroll
  for (int fi=0; fi<2; fi++)
  #pragma unroll
  for (int fj=0; fj<2; fj++)
  #pragma unroll
  for (int reg=0; reg<4; reg++){
    int ml = wr + fi*16 + (lane>>4)*4 + reg;
    int r = r0 + ml;
    if (r >= Mz) continue;
    int col = n0 + wc + fj*16 + (lane&15);
    float val = acc[fi][fj][reg] + bz[col];
    if (do_gelu){
      float xx = val;
      float t = tanhf(0.7978845608028654f*(xx + 0.044715f*xx*xx*xx));
      val = 0.5f*xx*(1.0f + t);
    }
    long long orow = (long long)obase + r;
    if (Cf) Cf[orow*ldc + col] = val;
    if (Cb) Cb[orow*ldc + col] = f2bf(val);
  }
}

// ---------------- K/V split preprocessing ----------------
// elementwise split: fp32 [n4*4] -> hi/lo bf16 planes (same layout)
__global__ __launch_bounds__(256) void kv_split_kernel(const float* __restrict__ in,
                                                       unsigned short* __restrict__ hi,
                                                       unsigned short* __restrict__ lo,
                                                       int n4){
  int i = blockIdx.x*256 + threadIdx.x;
  if (i >= n4) return;
  f32x4 v = *(const f32x4*)(in + (long long)i*4);
  unsigned int p0 = splitbf_pack(v.x), p1 = splitbf_pack(v.y);
  unsigned int p2 = splitbf_pack(v.z), p3 = splitbf_pack(v.w);
  us16x4 h, l;
  h.x=(unsigned short)p0; l.x=(unsigned short)(p0>>16);
  h.y=(unsigned short)p1; l.y=(unsigned short)(p1>>16);
  h.z=(unsigned short)p2; l.z=(unsigned short)(p2>>16);
  h.w=(unsigned short)p3; l.w=(unsigned short)(p3>>16);
  *(us16x4*)(hi + (long long)i*4) = h;
  *(us16x4*)(lo + (long long)i*4) = l;
}

// transpose-split V: vbuf [b*1024+s][g*64+d] fp32 -> vt[(b*4+g)*64+d][1024 s] hi/lo bf16
__global__ __launch_bounds__(256) void vt_split_kernel(const float* __restrict__ vin,
                                                       unsigned short* __restrict__ vth,
                                                       unsigned short* __restrict__ vtl){
  __shared__ float tile[32][33];
  int s0 = blockIdx.x*32, d0 = blockIdx.y*32;
  int bg = blockIdx.z; int b = bg >> 2, g = bg & 3;
  int tx = threadIdx.x, ty = threadIdx.y;
  #pragma unroll
  for (int i=0;i<4;i++){
    int r = ty + i*8;
    tile[r][tx] = vin[(long long)(b*1024 + s0 + r)*256 + g*64 + d0 + tx];
  }
  __syncthreads();
  #pragma unroll
  for (int i=0;i<4;i++){
    int d = d0 + ty + i*8;
    unsigned int pk = splitbf_pack(tile[tx][ty + i*8]);
    long long o = (long long)(bg*64 + d)*1024 + s0 + tx;
    vth[o] = (unsigned short)(pk & 0xFFFFu);
    vtl[o] = (unsigned short)(pk >> 16);
  }
}

// ---------------- MFMA flash attention, split-bf16x3 ----------------
// block = (64 q-rows, head, batch); 4 waves, wave w owns q-strip w*16..w*16+15 x all cols
#define AT_LDK 72   // bf16 stride for K / VT tiles in LDS
#define AT_LDP 76   // u32 stride for P strips
__global__ __launch_bounds__(256, 2) void attn_mfma(
    const float* __restrict__ q,
    const unsigned short* __restrict__ kh, const unsigned short* __restrict__ kl,
    const unsigned short* __restrict__ vth, const unsigned short* __restrict__ vtl,
    float* __restrict__ ctx, int causal)
{
  __shared__ __align__(16) unsigned short KhS[64*AT_LDK];
  __shared__ __align__(16) unsigned short KlS[64*AT_LDK];
  __shared__ __align__(16) unsigned short VhS[64*AT_LDK];
  __shared__ __align__(16) unsigned short VlS[64*AT_LDK];
  __shared__ __align__(16) unsigned int   Pp[4][16*AT_LDP];

  const int qblk = blockIdx.x;
  const int h = blockIdx.y;
  const int b = blockIdx.z;
  const int g = h / (H_/G_);
  const int tid = threadIdx.x;
  const int lane = tid & 63;
  const int w = tid >> 6;
  const int l15 = lane & 15;
  const int l4 = lane >> 4;
  const int qb0 = qblk*64;

  // load+split Q A-frags for this lane's strip row (scaled by 1/sqrt(64), exact pow2)
  short8 qh[2], ql[2];
  #pragma unroll
  for (int ks=0; ks<2; ks++){
    const float* qp = q + ((long long)(b*S_ + qb0 + w*16 + l15))*D_ + h*DH_ + ks*32 + l4*8;
    f32x4 q0 = *(const f32x4*)qp;
    f32x4 q1 = *(const f32x4*)(qp + 4);
    float qq[8] = {q0.x,q0.y,q0.z,q0.w,q1.x,q1.y,q1.z,q1.w};
    #pragma unroll
    for (int j=0;j<8;j++){
      unsigned int pk = splitbf_pack(qq[j]*0.125f);
      qh[ks][j] = (short)(pk & 0xFFFFu);
      ql[ks][j] = (short)(pk >> 16);
    }
  }

  f32x4 o[4];
  #pragma unroll
  for (int fd=0; fd<4; fd++) o[fd] = (f32x4){0.f,0.f,0.f,0.f};
  float m[4]    = {-3.0e38f,-3.0e38f,-3.0e38f,-3.0e38f};
  float lsum[4] = {0.f,0.f,0.f,0.f};

  const int ntiles = causal ? (qblk + 1) : (S_/64);
  for (int kt=0; kt<ntiles; kt++){
    __syncthreads();   // previous tile's LDS reads complete
    {
      int r = tid >> 2, c = tid & 3;
      long long krow = (long long)(b*S_ + kt*64 + r)*(G_*DH_) + g*DH_;
      long long vrow = (long long)((b*G_ + g)*64 + r)*S_ + kt*64;
      *(u32x4*)&KhS[r*AT_LDK + c*8]     = *(const u32x4*)(kh + krow + c*8);
      *(u32x4*)&KhS[r*AT_LDK + (c+4)*8] = *(const u32x4*)(kh + krow + (c+4)*8);
      *(u32x4*)&KlS[r*AT_LDK + c*8]     = *(const u32x4*)(kl + krow + c*8);
      *(u32x4*)&KlS[r*AT_LDK + (c+4)*8] = *(const u32x4*)(kl + krow + (c+4)*8);
      *(u32x4*)&VhS[r*AT_LDK + c*8]     = *(const u32x4*)(vth + vrow + c*8);
      *(u32x4*)&VhS[r*AT_LDK + (c+4)*8] = *(const u32x4*)(vth + vrow + (c+4)*8);
      *(u32x4*)&VlS[r*AT_LDK + c*8]     = *(const u32x4*)(vtl + vrow + c*8);
      *(u32x4*)&VlS[r*AT_LDK + (c+4)*8] = *(const u32x4*)(vtl + vrow + (c+4)*8);
    }
    __syncthreads();   // staging visible

    // QK^T: S-strip 16 x 64 per wave
    f32x4 s[4];
    #pragma unroll
    for (int fj=0; fj<4; fj++) s[fj] = (f32x4){0.f,0.f,0.f,0.f};
    #pragma unroll
    for (int ks=0; ks<2; ks++){
      #pragma unroll
      for (int fj=0; fj<4; fj++){
        short8 bh = *(const short8*)&KhS[(fj*16 + l15)*AT_LDK + ks*32 + l4*8];
        short8 bl = *(const short8*)&KlS[(fj*16 + l15)*AT_LDK + ks*32 + l4*8];
        s[fj] = __builtin_amdgcn_mfma_f32_16x16x32_bf16(qh[ks], bh, s[fj], 0,0,0);
        s[fj] = __builtin_amdgcn_mfma_f32_16x16x32_bf16(ql[ks], bh, s[fj], 0,0,0);
        s[fj] = __builtin_amdgcn_mfma_f32_16x16x32_bf16(qh[ks], bl, s[fj], 0,0,0);
      }
    }

    if (causal && kt == qblk){
      #pragma unroll
      for (int fj=0; fj<4; fj++){
        int key = kt*64 + fj*16 + l15;
        #pragma unroll
        for (int reg=0; reg<4; reg++){
          int qr = qb0 + w*16 + l4*4 + reg;
          if (key > qr) s[fj][reg] = -3.0e38f;
        }
      }
    }

    // online softmax (row stats via 16-lane shfl groups)
    float c[4], pmax[4];
    #pragma unroll
    for (int reg=0; reg<4; reg++){
      float mx = fmaxf(fmaxf(s[0][reg], s[1][reg]), fmaxf(s[2][reg], s[3][reg]));
      mx = fmaxf(mx, __shfl_xor(mx, 1));
      mx = fmaxf(mx, __shfl_xor(mx, 2));
      mx = fmaxf(mx, __shfl_xor(mx, 4));
      mx = fmaxf(mx, __shfl_xor(mx, 8));
      float mn = fmaxf(m[reg], mx);
      c[reg] = __expf(m[reg] - mn);
      m[reg] = mn;
      pmax[reg] = mn;
    }
    float psum[4] = {0.f,0.f,0.f,0.f};
    #pragma unroll
    for (int fj=0; fj<4; fj++){
      #pragma unroll
      for (int reg=0; reg<4; reg++){
        float pv = __expf(s[fj][reg] - pmax[reg]);
        psum[reg] += pv;
        Pp[w][(l4*4 + reg)*AT_LDP + fj*16 + l15] = splitbf_pack(pv);
      }
    }
    #pragma unroll
    for (int reg=0; reg<4; reg++){
      float ps = psum[reg];
      ps += __shfl_xor(ps, 1); ps += __shfl_xor(ps, 2);
      ps += __shfl_xor(ps, 4); ps += __shfl_xor(ps, 8);
      lsum[reg] = lsum[reg]*c[reg] + ps;
      o[0][reg] *= c[reg]; o[1][reg] *= c[reg];
      o[2][reg] *= c[reg]; o[3][reg] *= c[reg];
    }

    // PV: O-strip 16 x 64, A = P (from wave-local LDS), B = V^T
    #pragma unroll
    for (int ks=0; ks<2; ks++){
      u32x4 pa = *(const u32x4*)&Pp[w][l15*AT_LDP + ks*32 + l4*8];
      u32x4 pb = *(const u32x4*)&Pp[w][l15*AT_LDP + ks*32 + l4*8 + 4];
      short8 ph, pl;
      #pragma unroll
      for (int j=0;j<4;j++){
        ph[j]   = (short)(pa[j] & 0xFFFFu); pl[j]   = (short)(pa[j] >> 16);
        ph[4+j] = (short)(pb[j] & 0xFFFFu); pl[4+j] = (short)(pb[j] >> 16);
      }
      #pragma unroll
      for (int fd=0; fd<4; fd++){
        short8 vh = *(const short8*)&VhS[(fd*16 + l15)*AT_LDK + ks*32 + l4*8];
        short8 vl = *(const short8*)&VlS[(fd*16 + l15)*AT_LDK + ks*32 + l4*8];
        o[fd] = __builtin_amdgcn_mfma_f32_16x16x32_bf16(ph, vh, o[fd], 0,0,0);
        o[fd] = __builtin_amdgcn_mfma_f32_16x16x32_bf16(pl, vh, o[fd], 0,0,0);
        o[fd] = __builtin_amdgcn_mfma_f32_16x16x32_bf16(ph, vl, o[fd], 0,0,0);
      }
    }
  }

  #pragma unroll
  for (int reg=0; reg<4; reg++){
    float inv = 1.0f / lsum[reg];
    long long tok = b*S_ + qb0 + w*16 + l4*4 + reg;
    #pragma unroll
    for (int fd=0; fd<4; fd++){
      ctx[tok*D_ + h*DH_ + fd*16 + l15] = o[fd][reg]*inv;
    }
  }
}

// ---------------- MoE gate ----------------
__global__ __launch_bounds__(256) void gate_kernel(const float* __restrict__ xnf,
                                                   const float* __restrict__ gw,
                                                   const float* __restrict__ gb,
                                                   int* __restrict__ counts,
                                                   int* __restrict__ toklist,
                                                   int* __restrict__ route_e,
                                                   int* __restrict__ route_pos,
                                                   float* __restrict__ route_w){
  int t = blockIdx.x*4 + (threadIdx.x >> 6);
  int lane = threadIdx.x & 63;
  float acc[E_];
  #pragma unroll
  for (int e=0;e<E_;e++) acc[e] = 0.f;
  #pragma unroll
  for (int i=0;i<12;i++){
    int d = lane + 64*i;
    float xv = xnf[(long long)t*D_ + d];
    const float* w = gw + (long long)d*E_;
    #pragma unroll
    for (int e=0;e<E_;e++) acc[e] += xv*w[e];
  }
  #pragma unroll
  for (int off=32; off; off>>=1)
    #pragma unroll
    for (int e=0;e<E_;e++) acc[e] += __shfl_xor(acc[e], off);
  if (lane == 0){
    #pragma unroll
    for (int e=0;e<E_;e++) acc[e] += gb[e];
    int e0 = 0;
    #pragma unroll
    for (int e=1;e<E_;e++) if (acc[e] > acc[e0]) e0 = e;
    int e1 = -1;
    #pragma unroll
    for (int e=0;e<E_;e++) if (e != e0 && (e1 < 0 || acc[e] > acc[e1])) e1 = e;
    float w0 = 1.0f/(1.0f + __expf(acc[e1] - acc[e0]));
    float w1 = 1.0f - w0;
    int p0 = atomicAdd(&counts[e0], 1);
    int p1 = atomicAdd(&counts[e1], 1);
    toklist[e0*NTOK + p0] = t;
    toklist[e1*NTOK + p1] = t;
    route_e[2*t]   = e0; route_e[2*t+1]   = e1;
    route_pos[2*t] = p0; route_pos[2*t+1] = p1;
    route_w[2*t]   = w0; route_w[2*t+1]   = w1;
  }
}

__global__ void offsets_kernel(const int* __restrict__ counts, int* __restrict__ offs){
  if (threadIdx.x == 0){
    int s = 0;
    for (int e=0;e<E_;e++){ offs[e] = s; s += counts[e]; }
  }
}

__global__ __launch_bounds__(192) void combine_kernel(const float* __restrict__ xb,
                                                      const float* __restrict__ y,
                                                      const int* __restrict__ route_e,
                                                      const int* __restrict__ route_pos,
                                                      const float* __restrict__ route_w,
                                                      const int* __restrict__ offs,
                                                      float* __restrict__ out){
  int t = blockIdx.x;
  int i = threadIdx.x;
  int e0 = route_e[2*t], e1 = route_e[2*t+1];
  long long s0 = offs[e0] + route_pos[2*t];
  long long s1 = offs[e1] + route_pos[2*t+1];
  float w0 = route_w[2*t], w1 = route_w[2*t+1];
  f32x4 xv = *(const f32x4*)(xb + (long long)t*D_ + i*4);
  f32x4 y0 = *(const f32x4*)(y + s0*D_ + i*4);
  f32x4 y1 = *(const f32x4*)(y + s1*D_ + i*4);
  f32x4 o = xv + w0*y0 + w1*y1;
  *(f32x4*)(out + (long long)t*D_ + i*4) = o;
}

// ---------------- host orchestration ----------------
extern "C" void kernel_launch(void* const* d_in, const int* in_sizes, int n_in,
                              void* d_out, int out_size, void* d_ws, size_t ws_size,
                              hipStream_t stream) {
  (void)in_sizes; (void)n_in; (void)out_size; (void)ws_size;
  const float* x     = (const float*)d_in[0];
  const float* enc   = (const float*)d_in[1];
  const float* ln1s  = (const float*)d_in[2];
  const float* ln1b  = (const float*)d_in[3];
  const float* ln2s  = (const float*)d_in[4];
  const float* ln2b  = (const float*)d_in[5];
  const float* ln3s  = (const float*)d_in[6];
  const float* ln3b  = (const float*)d_in[7];
  const float* sa_wq = (const float*)d_in[8];
  const float* sa_bq = (const float*)d_in[9];
  const float* sa_wk = (const float*)d_in[10];
  const float* sa_bk = (const float*)d_in[11];
  const float* sa_wv = (const float*)d_in[12];
  const float* sa_bv = (const float*)d_in[13];
  const float* sa_wo = (const float*)d_in[14];
  const float* sa_bo = (const float*)d_in[15];
  const float* ca_wq = (const float*)d_in[16];
  const float* ca_bq = (const float*)d_in[17];
  const float* ca_wk = (const float*)d_in[18];
  const float* ca_bk = (const float*)d_in[19];
  const float* ca_wv = (const float*)d_in[20];
  const float* ca_bv = (const float*)d_in[21];
  const float* ca_wo = (const float*)d_in[22];
  const float* ca_bo = (const float*)d_in[23];
  const float* gate_w= (const float*)d_in[24];
  const float* gate_b= (const float*)d_in[25];
  const float* w1    = (const float*)d_in[26];
  const float* b1    = (const float*)d_in[27];
  const float* w2    = (const float*)d_in[28];
  const float* b2    = (const float*)d_in[29];
  float* out = (float*)d_out;

  char* p = (char*)d_ws;
  auto alloc = [&](size_t bytes)->void*{
    void* r = (void*)p;
    p += (bytes + 255) & ~(size_t)255;
    return r;
  };
  unsigned short* wqh_sa = (unsigned short*)alloc((size_t)D_*D_*2);
  unsigned short* wql_sa = (unsigned short*)alloc((size_t)D_*D_*2);
  unsigned short* wkh_sa = (unsigned short*)alloc((size_t)D_*G_*DH_*2);
  unsigned short* wkl_sa = (unsigned short*)alloc((size_t)D_*G_*DH_*2);
  unsigned short* wvh_sa = (unsigned short*)alloc((size_t)D_*G_*DH_*2);
  unsigned short* wvl_sa = (unsigned short*)alloc((size_t)D_*G_*DH_*2);
  unsigned short* woh_sa = (unsigned short*)alloc((size_t)D_*D_*2);
  unsigned short* wol_sa = (unsigned short*)alloc((size_t)D_*D_*2);
  unsigned short* wqh_ca = (unsigned short*)alloc((size_t)D_*D_*2);
  unsigned short* wql_ca = (unsigned short*)alloc((size_t)D_*D_*2);
  unsigned short* wkh_ca = (unsigned short*)alloc((size_t)D_*G_*DH_*2);
  unsigned short* wkl_ca = (unsigned short*)alloc((size_t)D_*G_*DH_*2);
  unsigned short* wvh_ca = (unsigned short*)alloc((size_t)D_*G_*DH_*2);
  unsigned short* wvl_ca = (unsigned short*)alloc((size_t)D_*G_*DH_*2);
  unsigned short* woh_ca = (unsigned short*)alloc((size_t)D_*D_*2);
  unsigned short* wol_ca = (unsigned short*)alloc((size_t)D_*D_*2);
  unsigned short* w1T = (unsigned short*)alloc((size_t)E_*D_*F_*2);
  unsigned short* w2T = (unsigned short*)alloc((size_t)E_*D_*F_*2);
  unsigned short* xn_b = (unsigned short*)alloc((size_t)NTOK*D_*2);
  unsigned short* hbuf = (unsigned short*)alloc((size_t)2*NTOK*F_*2);
  // K/V split planes (shared between self- and cross-attn, sequential use)
  unsigned short* khp = (unsigned short*)alloc((size_t)NTOK*G_*DH_*2);
  unsigned short* klp = (unsigned short*)alloc((size_t)NTOK*G_*DH_*2);
  unsigned short* vtp_h = (unsigned short*)alloc((size_t)NTOK*G_*DH_*2);
  unsigned short* vtp_l = (unsigned short*)alloc((size_t)NTOK*G_*DH_*2);
  float* xnf  = (float*)alloc((size_t)NTOK*D_*4);
  float* qbuf = (float*)alloc((size_t)NTOK*D_*4);
  float* kbuf = (float*)alloc((size_t)NTOK*G_*DH_*4);
  float* vbuf = (float*)alloc((size_t)NTOK*G_*DH_*4);
  float* ctx  = (float*)alloc((size_t)NTOK*D_*4);
  float* xbuf = (float*)alloc((size_t)NTOK*D_*4);
  float* ybuf = (float*)alloc((size_t)2*NTOK*D_*4);
  int* counts    = (int*)alloc(E_*4);
  int* offs      = (int*)alloc(E_*4);
  int* toklist   = (int*)alloc((size_t)E_*NTOK*4);
  int* route_e   = (int*)alloc((size_t)2*NTOK*4);
  int* route_pos = (int*)alloc((size_t)2*NTOK*4);
  float* route_w = (float*)alloc((size_t)2*NTOK*4);

  (void)hipMemsetAsync(counts, 0, E_*sizeof(int), stream);

  dim3 tb(32,8);
  tcast_kernel<<<dim3(24,24,1), tb, 0, stream>>>(sa_wq, wqh_sa, wql_sa, 768, 768);
  tcast_kernel<<<dim3( 8,24,1), tb, 0, stream>>>(sa_wk, wkh_sa, wkl_sa, 768, 256);
  tcast_kernel<<<dim3( 8,24,1), tb, 0, stream>>>(sa_wv, wvh_sa, wvl_sa, 768, 256);
  tcast_kernel<<<dim3(24,24,1), tb, 0, stream>>>(sa_wo, woh_sa, wol_sa, 768, 768);
  tcast_kernel<<<dim3(24,24,1), tb, 0, stream>>>(ca_wq, wqh_ca, wql_ca, 768, 768);
  tcast_kernel<<<dim3( 8,24,1), tb, 0, stream>>>(ca_wk, wkh_ca, wkl_ca, 768, 256);
  tcast_kernel<<<dim3( 8,24,1), tb, 0, stream>>>(ca_wv, wvh_ca, wvl_ca, 768, 256);
  tcast_kernel<<<dim3(24,24,1), tb, 0, stream>>>(ca_wo, woh_ca, wol_ca, 768, 768);
  tcast_kernel<<<dim3(96,24,E_), tb, 0, stream>>>(w1, w1T, nullptr, 768, 3072);
  tcast_kernel<<<dim3(24,96,E_), tb, 0, stream>>>(w2, w2T, nullptr, 3072, 768);

  // ---- self-attention ----
  ln_kernel<<<NTOK, 256, 0, stream>>>(x, ln1s, ln1b, nullptr, xnf);
  gemm_split<<<dim3(12,32), 256, 0, stream>>>(xnf, 768, wqh_sa, wql_sa, sa_bq, nullptr, qbuf, 768, 768);
  gemm_split<<<dim3( 4,32), 256, 0, stream>>>(xnf, 768, wkh_sa, wkl_sa, sa_bk, nullptr, kbuf, 256, 768);
  gemm_split<<<dim3( 4,32), 256, 0, stream>>>(xnf, 768, wvh_sa, wvl_sa, sa_bv, nullptr, vbuf, 256, 768);
  kv_split_kernel<<<dim3(NTOK*G_*DH_/4/256), 256, 0, stream>>>(kbuf, khp, klp, NTOK*G_*DH_/4);
  vt_split_kernel<<<dim3(32,2,8), tb, 0, stream>>>(vbuf, vtp_h, vtp_l);
  attn_mfma<<<dim3(16,12,2), 256, 0, stream>>>(qbuf, khp, klp, vtp_h, vtp_l, ctx, 1);
  gemm_split<<<dim3(12,32), 256, 0, stream>>>(ctx, 768, woh_sa, wol_sa, sa_bo, x, xbuf, 768, 768);

  // ---- cross-attention ----
  ln_kernel<<<NTOK, 256, 0, stream>>>(xbuf, ln2s, ln2b, nullptr, xnf);
  gemm_split<<<dim3(12,32), 256, 0, stream>>>(xnf, 768, wqh_ca, wql_ca, ca_bq, nullptr, qbuf, 768, 768);
  gemm_split<<<dim3( 4,32), 256, 0, stream>>>(enc, 768, wkh_ca, wkl_ca, ca_bk, nullptr, kbuf, 256, 768);
  gemm_split<<<dim3( 4,32), 256, 0, stream>>>(enc, 768, wvh_ca, wvl_ca, ca_bv, nullptr, vbuf, 256, 768);
  kv_split_kernel<<<dim3(NTOK*G_*DH_/4/256), 256, 0, stream>>>(kbuf, khp, klp, NTOK*G_*DH_/4);
  vt_split_kernel<<<dim3(32,2,8), tb, 0, stream>>>(vbuf, vtp_h, vtp_l);
  attn_mfma<<<dim3(16,12,2), 256, 0, stream>>>(qbuf, khp, klp, vtp_h, vtp_l, ctx, 0);
  gemm_split<<<dim3(12,32), 256, 0, stream>>>(ctx, 768, woh_ca, wol_ca, ca_bo, xbuf, xbuf, 768, 768);

  // ---- MoE ----
  ln_kernel<<<NTOK, 256, 0, stream>>>(xbuf, ln3s, ln3b, xn_b, xnf);
  gate_kernel<<<NTOK/4, 256, 0, stream>>>(xnf, gate_w, gate_b,
      counts, toklist, route_e, route_pos, route_w);
  offsets_kernel<<<1, 64, 0, stream>>>(counts, offs);
  gemm_nt<<<dim3(48,32,E_), 256, 0, stream>>>(xn_b, 768, w1T, (long long)F_*D_, b1, F_,
      counts, toklist, NTOK, offs, nullptr, hbuf, F_, NTOK, 768, 1);
  gemm_nt<<<dim3(12,32,E_), 256, 0, stream>>>(hbuf, F_, w2T, (long long)F_*D_, b2, D_,
      counts, nullptr, 0, offs, ybuf, nullptr, 768, NTOK, F_, 0);
  combine_kernel<<<NTOK, 192, 0, stream>>>(xbuf, ybuf, route_e, route_pos, route_w, offs, out);
}